// Round 15
// baseline (572.364 us; speedup 1.0000x reference)
//
#include <hip/hip_runtime.h>

#define NN 100000
#define NE 3200000
#define HD 64

// two-phase CSR build (packed 4-B pair entries: src | local_dst<<17)
#define NBUCK 256
#define BWID 392                                    // 256*392 = 100352 >= NN
#define SLACK 20480                                 // slots/bucket (8-granular runs, ~18.5K exp)
#define COLCAP 13568                                // real cols/bucket cap (12544 + ~9 sigma)
#define OVFCAP 512                                  // overflow pairs/bucket
#define CAP 24                                      // staged entries per bucket per block
#define P1_EPB 2048                                 // edges per partition block
#define P1_GRID ((NE + P1_EPB - 1) / P1_EPB)        // 1563
#define PSENT 0xFFFFFFFFu                           // sentinel pad entry

typedef int      v4i __attribute__((ext_vector_type(4)));
typedef int      v2i __attribute__((ext_vector_type(2)));
typedef _Float16 h4f __attribute__((ext_vector_type(4)));   // 4 halves = 8 B
typedef _Float16 h8f __attribute__((ext_vector_type(8)));   // 8 halves = 16 B

__device__ __forceinline__ void fma4(float4& a, float s, const float4& b) {
    a.x = fmaf(s, b.x, a.x); a.y = fmaf(s, b.y, a.y);
    a.z = fmaf(s, b.z, a.z); a.w = fmaf(s, b.w, a.w);
}

// ---------------- phase 1: bucket partition, LDS-staged, 1 drain/block ----------------
// 4-B packed entries; drain flushes ceil(c/8)*8 slots (32-B runs). Adjacent
// half-lines of one bucket land while the line is L2-open (256 open lines =
// 16 KB) -> no partial-line writeback amplification.
__global__ void __launch_bounds__(256) partition_kernel(
    const int* __restrict__ src, const int* __restrict__ dst,
    int* __restrict__ bctl, unsigned* __restrict__ pairs, v2i* __restrict__ povf) {
    __shared__ unsigned stage[NBUCK][CAP];
    __shared__ int cnt[NBUCK];
    int t = threadIdx.x;
    cnt[t] = 0;                         // NBUCK == blockDim == 256
    __syncthreads();
    const v4i* d4p = (const v4i*)dst;
    const v4i* s4p = (const v4i*)src;
    const int NE4 = NE / 4;
    int base4 = blockIdx.x * (P1_EPB / 4);
    #pragma unroll
    for (int it = 0; it < P1_EPB / 1024; it++) {
        int i = base4 + it * 256 + t;
        v4i d4 = (v4i){-1, -1, -1, -1};
        v4i s4 = (v4i){0, 0, 0, 0};
        if (i < NE4) {
            d4 = __builtin_nontemporal_load(d4p + i);
            s4 = __builtin_nontemporal_load(s4p + i);
        }
        #pragma unroll
        for (int k = 0; k < 4; k++) {
            int d = d4[k];
            if (d >= 0) {
                int b = (unsigned)d / BWID;
                int slot = atomicAdd(&cnt[b], 1);
                unsigned u = (unsigned)s4[k] | ((unsigned)(d - b * BWID) << 17);
                if (slot < CAP) {
                    stage[b][slot] = u;
                } else {                 // rare overflow -> separate region
                    int o = atomicAdd(&bctl[b * 16 + 2], 1);
                    v2i p; p[0] = s4[k]; p[1] = d;
                    if (o < OVFCAP) povf[(size_t)b * OVFCAP + o] = p;
                }
            }
        }
    }
    __syncthreads();
    // drain bucket t (single drain per block)
    int c_tot = cnt[t];
    int c = (c_tot > CAP) ? CAP : c_tot;
    int runs = (c + 7) >> 3;             // 0..3
    if (runs) {
        int slots = runs * 8;            // 8/16/24
        for (int m = c; m < slots; m++) stage[t][m] = PSENT;
        int gb = atomicAdd(&bctl[t * 16], slots);   // stays multiple of 8
        if (gb + slots <= SLACK) {
            v4i* gp = (v4i*)(pairs + (size_t)t * SLACK + gb);
            const v4i* sp = (const v4i*)&stage[t][0];
            #pragma unroll
            for (int m = 0; m < 6; m++) { if (m < runs * 2) gp[m] = sp[m]; }
        } else {
            for (int m = 0; m < slots && gb + m < SLACK; m++)
                pairs[(size_t)t * SLACK + gb + m] = stage[t][m];
        }
    }
    if (c_tot > 0) atomicAdd(&bctl[t * 16 + 1], c_tot);   // real contribution
}

// ---------------- phase 2: bucket scan + per-bucket hist + scan + LDS scatter ----------
// One block per bucket. Includes the global bucket prefix-scan (256 loads +
// LDS scan per block -- replaces the separate bucket_scan kernel) and folds
// the hA/hB sentinel zero-row writes (replaces 2 memset launches).
__global__ void __launch_bounds__(256) csr_fill_kernel(
    const unsigned* __restrict__ pairs, const v2i* __restrict__ povf,
    const int* __restrict__ bctl, int* __restrict__ rowptr,
    float* __restrict__ dinv, int* __restrict__ col,
    _Float16* __restrict__ hA, _Float16* __restrict__ hB) {
    __shared__ int hist[BWID];
    __shared__ int rp[BWID];
    __shared__ int cur[BWID];
    __shared__ int sc[256];
    __shared__ int cols[COLCAP];
    int b = blockIdx.x, t = threadIdx.x;
    if (b == 0 && t < 64) {             // sentinel zero rows
        hA[(size_t)NN * 64 + t] = (_Float16)0.f;
        hB[(size_t)NN * 64 + t] = (_Float16)0.f;
    }
    int lo = b * BWID;
    int hi = min(lo + BWID, NN);
    int nw = hi - lo;
    // global bucket prefix scan (inclusive -> exclusive base for bucket b)
    int bcv = bctl[t * 16 + 1];
    sc[t] = bcv; __syncthreads();
    for (int off = 1; off < 256; off <<= 1) {
        int x = (t >= off) ? sc[t - off] : 0;
        __syncthreads();
        sc[t] += x;
        __syncthreads();
    }
    int base = (b > 0) ? sc[b - 1] : 0;
    if (b == 0 && t == 255) rowptr[NN] = sc[255];   // == NE
    __syncthreads();
    for (int i = t; i < BWID; i += 256) { hist[i] = 0; cur[i] = 0; }
    __syncthreads();
    int np = bctl[b * 16];     if (np > SLACK) np = SLACK;
    int nov = bctl[b * 16 + 2]; if (nov > OVFCAP) nov = OVFCAP;
    const unsigned* pb = pairs + (size_t)b * SLACK;
    const v2i* ob = povf + (size_t)b * OVFCAP;
    // pass 1: histogram (skip sentinels)
    for (int i = t; i < np; i += 256) {
        unsigned u = pb[i];
        if (u != PSENT) atomicAdd(&hist[(u >> 17) & 0x1FF], 1);
    }
    for (int i = t; i < nov; i += 256) {
        v2i p = ob[i];
        atomicAdd(&hist[p[1] - lo], 1);
    }
    __syncthreads();
    // exclusive scan of hist -> rp (2 elements per thread)
    int h0 = 0, s2 = 0;
    if (2 * t < BWID) {
        h0 = hist[2 * t];
        int h1 = (2 * t + 1 < BWID) ? hist[2 * t + 1] : 0;
        s2 = h0 + h1;
    }
    sc[t] = s2; __syncthreads();
    for (int off = 1; off < 256; off <<= 1) {
        int x = (t >= off) ? sc[t - off] : 0;
        __syncthreads();
        sc[t] += x;
        __syncthreads();
    }
    if (2 * t < BWID) {
        int ex = sc[t] - s2;
        rp[2 * t] = ex;
        if (2 * t + 1 < BWID) rp[2 * t + 1] = ex + h0;
    }
    __syncthreads();
    // rowptr + dinv slices (coalesced)
    for (int i = t; i < nw; i += 256) {
        rowptr[lo + i] = base + rp[i];
        dinv[lo + i] = 1.0f / sqrtf((float)(hist[i] + 1));  // +1 self-loop
    }
    // pass 2: scatter into LDS
    for (int i = t; i < np; i += 256) {
        unsigned u = pb[i];
        if (u != PSENT) {
            int li = (u >> 17) & 0x1FF;
            int slot = atomicAdd(&cur[li], 1);
            int o = rp[li] + slot;
            if (o < COLCAP) cols[o] = (int)(u & 0x1FFFF);
        }
    }
    for (int i = t; i < nov; i += 256) {
        v2i p = ob[i];
        int li = p[1] - lo;
        int slot = atomicAdd(&cur[li], 1);
        int o = rp[li] + slot;
        if (o < COLCAP) cols[o] = p[0];
    }
    __syncthreads();
    // contiguous col write (real count only)
    int nreal = bctl[b * 16 + 1]; if (nreal > COLCAP) nreal = COLCAP;
    for (int i = t; i < nreal; i += 256)
        col[base + i] = cols[i];
}

// ---------------- fused modality encoders + GCN layer-0 matmul ----------------
// Computes in fp32, stores hs = h*dinv as FP16.
__global__ void __launch_bounds__(256) encmm0_kernel(
    const float* __restrict__ xf, const float* __restrict__ xw, const float* __restrict__ xt,
    const float* __restrict__ Wf, const float* __restrict__ bf,
    const float* __restrict__ Ww, const float* __restrict__ bw,
    const float* __restrict__ Wt, const float* __restrict__ bt,
    const float* __restrict__ W0, const float* __restrict__ dinv,
    _Float16* __restrict__ h) {
    __shared__ float xin[64][32];    // fire[0..7], wea[8..19], ter[20..29]
    __shared__ float wenc[30][64];   // encoder weights (rows match xin cols)
    __shared__ float bs[192];        // encoder biases
    __shared__ float xs[64][36];     // encoder outputs for current 32-slice (+4 pad)
    __shared__ float ws[32][64];     // W0 rows for current slice
    int t = threadIdx.x;
    int n0 = blockIdx.x * 64;

    {   // stage raw inputs
        const float4* xf4 = (const float4*)xf;
        for (int i = t; i < 128; i += 256) {
            int n = i >> 1, q = i & 1;
            int gn = n0 + n;
            float4 v = make_float4(0, 0, 0, 0);
            if (gn < NN) v = xf4[(size_t)gn * 2 + q];
            *(float4*)&xin[n][q * 4] = v;
        }
        const float4* xw4 = (const float4*)xw;
        for (int i = t; i < 192; i += 256) {
            int n = i / 3, q = i - n * 3;
            int gn = n0 + n;
            float4 v = make_float4(0, 0, 0, 0);
            if (gn < NN) v = xw4[(size_t)gn * 3 + q];
            *(float4*)&xin[n][8 + q * 4] = v;
        }
        const float2* xt2 = (const float2*)xt;
        for (int i = t; i < 320; i += 256) {
            int n = i / 5, q = i - n * 5;
            int gn = n0 + n;
            float2 v = make_float2(0, 0);
            if (gn < NN) v = xt2[(size_t)gn * 5 + q];
            *(float2*)&xin[n][20 + q * 2] = v;
        }
        // stage encoder weights: rows 0-7 Wf, 8-19 Ww, 20-29 Wt
        for (int i = t; i < 480; i += 256) {
            int r = i >> 4, q = i & 15;
            float4 v;
            if (r < 8)       v = ((const float4*)Wf)[r * 16 + q];
            else if (r < 20) v = ((const float4*)Ww)[(r - 8) * 16 + q];
            else             v = ((const float4*)Wt)[(r - 20) * 16 + q];
            *(float4*)&wenc[r][q * 4] = v;
        }
        // stage encoder biases
        if (t < 192) bs[t] = (t < 64) ? bf[t] : (t < 128) ? bw[t - 64] : bt[t - 128];
    }

    int cg = t & 15, ng = t >> 4;
    int c0 = cg * 4;
    float4 acc[4];
    #pragma unroll
    for (int i = 0; i < 4; i++) acc[i] = make_float4(0, 0, 0, 0);

    for (int kq = 0; kq < 6; kq++) {
        __syncthreads();
        {   // stage W0 slice rows [kq*32, kq*32+32)
            const float4* W04 = (const float4*)W0;
            float4* ws4 = (float4*)&ws[0][0];
            for (int i = t; i < 512; i += 256)
                ws4[i] = W04[(size_t)kq * 512 + i];
        }
        // compute encoder outputs for this slice (uniform modality per kq)
        int coff = (kq < 2) ? kq * 32 : (kq < 4) ? (kq - 2) * 32 : (kq - 4) * 32;
        if (kq < 2) {
            for (int i = t; i < 2048; i += 256) {
                int n = i >> 5, kk = i & 31;
                float a = bs[kq * 32 + kk];
                #pragma unroll
                for (int k = 0; k < 8; k++) a = fmaf(xin[n][k], wenc[k][coff + kk], a);
                xs[n][kk] = fmaxf(a, 0.f);
            }
        } else if (kq < 4) {
            for (int i = t; i < 2048; i += 256) {
                int n = i >> 5, kk = i & 31;
                float a = bs[kq * 32 + kk];
                #pragma unroll
                for (int k = 0; k < 12; k++) a = fmaf(xin[n][8 + k], wenc[8 + k][coff + kk], a);
                xs[n][kk] = fmaxf(a, 0.f);
            }
        } else {
            for (int i = t; i < 2048; i += 256) {
                int n = i >> 5, kk = i & 31;
                float a = bs[kq * 32 + kk];
                #pragma unroll
                for (int k = 0; k < 10; k++) a = fmaf(xin[n][20 + k], wenc[20 + k][coff + kk], a);
                xs[n][kk] = fmaxf(a, 0.f);
            }
        }
        __syncthreads();
        // register-blocked fma over this 32-slice
        for (int k = 0; k < 32; k += 4) {
            float4 b0 = *(const float4*)&ws[k + 0][c0];
            float4 b1 = *(const float4*)&ws[k + 1][c0];
            float4 b2 = *(const float4*)&ws[k + 2][c0];
            float4 b3 = *(const float4*)&ws[k + 3][c0];
            #pragma unroll
            for (int i = 0; i < 4; i++) {
                float4 a = *(const float4*)&xs[ng * 4 + i][k];
                fma4(acc[i], a.x, b0); fma4(acc[i], a.y, b1);
                fma4(acc[i], a.z, b2); fma4(acc[i], a.w, b3);
            }
        }
    }
    h4f* h4 = (h4f*)h;
    #pragma unroll
    for (int i = 0; i < 4; i++) {
        int gn = n0 + ng * 4 + i;
        if (gn < NN) {
            float dn = dinv[gn];
            h4f v;
            v[0] = (_Float16)(acc[i].x * dn);
            v[1] = (_Float16)(acc[i].y * dn);
            v[2] = (_Float16)(acc[i].z * dn);
            v[3] = (_Float16)(acc[i].w * dn);
            h4[((unsigned)gn << 4) + cg] = v;
        }
    }
}

__device__ __forceinline__ void addh8(float* a, const h8f& b) {
    #pragma unroll
    for (int k = 0; k < 8; k++) a[k] += (float)b[k];
}

// ---------------- fused CSR gather + finalize + next-layer 64x64 matmul ----------------
// 16-B/lane fp16 loads: q = l&7 (8 x 16B slots per 128-B row), g = l>>3
// (8 edge subslots) -> each VMEM instruction covers 8 edges instead of 4,
// halving the gather's load-instruction count (the measured invariant across
// fp32/fp16 was instr count, not bytes -> VMEM-request-bound).
__global__ void gather_mm_kernel(
    const int* __restrict__ col, const int* __restrict__ rowptr,
    const float* __restrict__ dinv, const _Float16* __restrict__ h,
    const float* __restrict__ bias, const float* __restrict__ W,
    _Float16* __restrict__ hout) {
    int t = threadIdx.x;
    int n = (blockIdx.x * 256 + t) >> 6;
    int l = t & 63;
    if (n >= NN) return;
    int g = l >> 3;      // edge sub-slot 0..7
    int q = l & 7;       // 16-B slot 0..7
    const h8f* h8 = (const h8f*)h;
    // hoisted independent loads (in flight under the gather)
    float dn = dinv[n];
    h8f hnh = h8[((unsigned)n << 3) + q];
    float4 ba = ((const float4*)bias)[q * 2];
    float4 bb = ((const float4*)bias)[q * 2 + 1];
    float acc[8] = {0, 0, 0, 0, 0, 0, 0, 0};
    int r0 = rowptr[n], r1 = rowptr[n + 1];
    for (int base = r0; base < r1; base += 64) {
        int cnt = min(64, r1 - base);
        int pv = NN;                          // sentinel: zero row
        if (l < cnt) pv = __builtin_nontemporal_load(col + base + l);
        int steps = (cnt + 7) >> 3;           // <= 8
        int j = 0;
        for (; j + 4 <= steps; j += 4) {      // deg>=32 fast path: 4 loads = 32 edges
            int s0 = __shfl(pv, (j + 0) * 8 + g);
            int s1 = __shfl(pv, (j + 1) * 8 + g);
            int s2 = __shfl(pv, (j + 2) * 8 + g);
            int s3 = __shfl(pv, (j + 3) * 8 + g);
            h8f v0 = h8[((unsigned)s0 << 3) + q];
            h8f v1 = h8[((unsigned)s1 << 3) + q];
            h8f v2 = h8[((unsigned)s2 << 3) + q];
            h8f v3 = h8[((unsigned)s3 << 3) + q];
            addh8(acc, v0); addh8(acc, v1); addh8(acc, v2); addh8(acc, v3);
        }
        for (; j < steps; j++) {
            int s0 = __shfl(pv, j * 8 + g);
            h8f v0 = h8[((unsigned)s0 << 3) + q];
            addh8(acc, v0);
        }
    }
    // reduce across g (bits 3,4,5)
    #pragma unroll
    for (int k = 0; k < 8; k++) {
        acc[k] += __shfl_xor(acc[k], 8);
        acc[k] += __shfl_xor(acc[k], 16);
        acc[k] += __shfl_xor(acc[k], 32);
    }
    // layer output r (lane holds row halves q*8..q*8+7, replicated over g)
    float r[8];
    r[0] = fmaxf(fmaf(dn, acc[0] + (float)hnh[0], ba.x), 0.f);
    r[1] = fmaxf(fmaf(dn, acc[1] + (float)hnh[1], ba.y), 0.f);
    r[2] = fmaxf(fmaf(dn, acc[2] + (float)hnh[2], ba.z), 0.f);
    r[3] = fmaxf(fmaf(dn, acc[3] + (float)hnh[3], ba.w), 0.f);
    r[4] = fmaxf(fmaf(dn, acc[4] + (float)hnh[4], bb.x), 0.f);
    r[5] = fmaxf(fmaf(dn, acc[5] + (float)hnh[5], bb.y), 0.f);
    r[6] = fmaxf(fmaf(dn, acc[6] + (float)hnh[6], bb.z), 0.f);
    r[7] = fmaxf(fmaf(dn, acc[7] + (float)hnh[7], bb.w), 0.f);
    // next-layer matmul: lane l computes output column l; W rows from L1.
    // r_full[qq*8+k] = shfl(r[k], qq)  (lane qq has q==qq, g==0)
    float oc0 = 0.f, oc1 = 0.f, oc2 = 0.f, oc3 = 0.f;
    #pragma unroll
    for (int qq = 0; qq < 8; qq++) {
        float r0b = __shfl(r[0], qq);
        float r1b = __shfl(r[1], qq);
        float r2b = __shfl(r[2], qq);
        float r3b = __shfl(r[3], qq);
        float r4b = __shfl(r[4], qq);
        float r5b = __shfl(r[5], qq);
        float r6b = __shfl(r[6], qq);
        float r7b = __shfl(r[7], qq);
        oc0 = fmaf(r0b, W[(qq * 8 + 0) * 64 + l], oc0);
        oc1 = fmaf(r1b, W[(qq * 8 + 1) * 64 + l], oc1);
        oc2 = fmaf(r2b, W[(qq * 8 + 2) * 64 + l], oc2);
        oc3 = fmaf(r3b, W[(qq * 8 + 3) * 64 + l], oc3);
        oc0 = fmaf(r4b, W[(qq * 8 + 4) * 64 + l], oc0);
        oc1 = fmaf(r5b, W[(qq * 8 + 5) * 64 + l], oc1);
        oc2 = fmaf(r6b, W[(qq * 8 + 6) * 64 + l], oc2);
        oc3 = fmaf(r7b, W[(qq * 8 + 7) * 64 + l], oc3);
    }
    float oc = (oc0 + oc1) + (oc2 + oc3);
    __builtin_nontemporal_store((_Float16)(oc * dn), &hout[((unsigned)n << 6) + l]);
}

// ---------------- fused CSR gather + finalize + output MLP ----------------
__global__ void gather_mlp_kernel(
    const int* __restrict__ col, const int* __restrict__ rowptr,
    const float* __restrict__ dinv, const _Float16* __restrict__ h,
    const float* __restrict__ bias, const float* __restrict__ w1,
    const float* __restrict__ b1, const float* __restrict__ w2,
    const float* __restrict__ b2, float* __restrict__ out) {
    int t = threadIdx.x;
    int n = (blockIdx.x * 256 + t) >> 6;
    int l = t & 63;
    if (n >= NN) return;
    int g = l >> 3;
    int q = l & 7;
    const h8f* h8 = (const h8f*)h;
    float dn = dinv[n];
    h8f hnh = h8[((unsigned)n << 3) + q];
    float4 ba = ((const float4*)bias)[q * 2];
    float4 bb = ((const float4*)bias)[q * 2 + 1];
    float acc[8] = {0, 0, 0, 0, 0, 0, 0, 0};
    int r0 = rowptr[n], r1 = rowptr[n + 1];
    for (int base = r0; base < r1; base += 64) {
        int cnt = min(64, r1 - base);
        int pv = NN;
        if (l < cnt) pv = __builtin_nontemporal_load(col + base + l);
        int steps = (cnt + 7) >> 3;
        int j = 0;
        for (; j + 4 <= steps; j += 4) {
            int s0 = __shfl(pv, (j + 0) * 8 + g);
            int s1 = __shfl(pv, (j + 1) * 8 + g);
            int s2 = __shfl(pv, (j + 2) * 8 + g);
            int s3 = __shfl(pv, (j + 3) * 8 + g);
            h8f v0 = h8[((unsigned)s0 << 3) + q];
            h8f v1 = h8[((unsigned)s1 << 3) + q];
            h8f v2 = h8[((unsigned)s2 << 3) + q];
            h8f v3 = h8[((unsigned)s3 << 3) + q];
            addh8(acc, v0); addh8(acc, v1); addh8(acc, v2); addh8(acc, v3);
        }
        for (; j < steps; j++) {
            int s0 = __shfl(pv, j * 8 + g);
            h8f v0 = h8[((unsigned)s0 << 3) + q];
            addh8(acc, v0);
        }
    }
    #pragma unroll
    for (int k = 0; k < 8; k++) {
        acc[k] += __shfl_xor(acc[k], 8);
        acc[k] += __shfl_xor(acc[k], 16);
        acc[k] += __shfl_xor(acc[k], 32);
    }
    float r[8];
    r[0] = fmaxf(fmaf(dn, acc[0] + (float)hnh[0], ba.x), 0.f);
    r[1] = fmaxf(fmaf(dn, acc[1] + (float)hnh[1], ba.y), 0.f);
    r[2] = fmaxf(fmaf(dn, acc[2] + (float)hnh[2], ba.z), 0.f);
    r[3] = fmaxf(fmaf(dn, acc[3] + (float)hnh[3], ba.w), 0.f);
    r[4] = fmaxf(fmaf(dn, acc[4] + (float)hnh[4], bb.x), 0.f);
    r[5] = fmaxf(fmaf(dn, acc[5] + (float)hnh[5], bb.y), 0.f);
    r[6] = fmaxf(fmaf(dn, acc[6] + (float)hnh[6], bb.z), 0.f);
    r[7] = fmaxf(fmaf(dn, acc[7] + (float)hnh[7], bb.w), 0.f);
    // output MLP: hidden unit c = l&31 (w1 rows are L1-resident, coalesced)
    int c = l & 31;
    float a0 = b1[c], a1 = 0.f, a2p = 0.f, a3 = 0.f;
    #pragma unroll
    for (int qq = 0; qq < 8; qq++) {
        float r0b = __shfl(r[0], qq);
        float r1b = __shfl(r[1], qq);
        float r2b = __shfl(r[2], qq);
        float r3b = __shfl(r[3], qq);
        float r4b = __shfl(r[4], qq);
        float r5b = __shfl(r[5], qq);
        float r6b = __shfl(r[6], qq);
        float r7b = __shfl(r[7], qq);
        a0  = fmaf(r0b, w1[(qq * 8 + 0) * 32 + c], a0);
        a1  = fmaf(r1b, w1[(qq * 8 + 1) * 32 + c], a1);
        a2p = fmaf(r2b, w1[(qq * 8 + 2) * 32 + c], a2p);
        a3  = fmaf(r3b, w1[(qq * 8 + 3) * 32 + c], a3);
        a0  = fmaf(r4b, w1[(qq * 8 + 4) * 32 + c], a0);
        a1  = fmaf(r5b, w1[(qq * 8 + 5) * 32 + c], a1);
        a2p = fmaf(r6b, w1[(qq * 8 + 6) * 32 + c], a2p);
        a3  = fmaf(r7b, w1[(qq * 8 + 7) * 32 + c], a3);
    }
    float a = (a0 + a1) + (a2p + a3);
    float v = fmaxf(a, 0.f) * w2[c];
    v += __shfl_xor(v, 1); v += __shfl_xor(v, 2);
    v += __shfl_xor(v, 4); v += __shfl_xor(v, 8);
    v += __shfl_xor(v, 16);
    if (l == 0) __builtin_nontemporal_store(v + b2[0], &out[n]);
}

extern "C" void kernel_launch(void* const* d_in, const int* in_sizes, int n_in,
                              void* d_out, int out_size, void* d_ws, size_t ws_size,
                              hipStream_t stream) {
    const float* xf = (const float*)d_in[0];
    const float* xw = (const float*)d_in[1];
    const float* xt = (const float*)d_in[2];
    const int*   ei = (const int*)d_in[3];
    const int*   src = ei;
    const int*   dst = ei + NE;
    const float* Wf = (const float*)d_in[4];
    const float* bf = (const float*)d_in[5];
    const float* Ww = (const float*)d_in[6];
    const float* bw = (const float*)d_in[7];
    const float* Wt = (const float*)d_in[8];
    const float* bt = (const float*)d_in[9];
    const float* W0 = (const float*)d_in[10];
    const float* b0 = (const float*)d_in[11];
    const float* W1 = (const float*)d_in[12];
    const float* b1 = (const float*)d_in[13];
    const float* W2 = (const float*)d_in[14];
    const float* b2 = (const float*)d_in[15];
    const float* ow1 = (const float*)d_in[16];
    const float* ob1 = (const float*)d_in[17];
    const float* ow2 = (const float*)d_in[18];
    const float* ob2 = (const float*)d_in[19];
    float* out = (float*)d_out;

    // workspace layout (~62 MB)
    char* w = (char*)d_ws;
    _Float16* hA  = (_Float16*)w;  w += (size_t)(NN + 1) * 64 * 2;   // 12.8 MB (+zero row)
    _Float16* hB  = (_Float16*)w;  w += (size_t)(NN + 1) * 64 * 2;   // 12.8 MB (+zero row)
    int*   col    = (int*)w;    w += (size_t)NE * 4;                 // 12.8 MB
    unsigned* pairs = (unsigned*)w; w += (size_t)NBUCK * SLACK * 4;  // 21 MB
    v2i*   povf   = (v2i*)w;    w += (size_t)NBUCK * OVFCAP * 8;     // 1 MB
    float* dinv   = (float*)w;  w += (size_t)NN * 4;
    int*   rowptr = (int*)w;    w += (size_t)(NN + 1) * 4;
    int*   bctl   = (int*)w;    w += (size_t)NBUCK * 16 * 4;         // 16 KB (padded lines)

    // ---- CSR build (two-phase, packed 4-B entries; reused by all 3 layers) ----
    hipMemsetAsync(bctl, 0, (size_t)NBUCK * 16 * 4, stream);
    partition_kernel<<<P1_GRID, 256, 0, stream>>>(src, dst, bctl, pairs, povf);
    csr_fill_kernel<<<NBUCK, 256, 0, stream>>>(pairs, povf, bctl, rowptr, dinv, col, hA, hB);

    // ---- layer 0: fused encoders + matmul (scaled) -> hA ----
    encmm0_kernel<<<(NN + 63) / 64, 256, 0, stream>>>(xf, xw, xt, Wf, bf, Ww, bw, Wt, bt, W0, dinv, hA);
    // ---- gather(b0) + mm(W1) : hA -> hB ----
    gather_mm_kernel<<<(NN * 64 + 255) / 256, 256, 0, stream>>>(col, rowptr, dinv, hA, b0, W1, hB);
    // ---- gather(b1) + mm(W2) : hB -> hA ----
    gather_mm_kernel<<<(NN * 64 + 255) / 256, 256, 0, stream>>>(col, rowptr, dinv, hB, b1, W2, hA);
    // ---- gather(b2) + output MLP : hA -> out ----
    gather_mlp_kernel<<<(NN * 64 + 255) / 256, 256, 0, stream>>>(col, rowptr, dinv, hA, b2, ow1, ob1, ow2, ob2, out);
}

// Round 16
// 549.896 us; speedup vs baseline: 1.0409x; 1.0409x over previous
//
#include <hip/hip_runtime.h>

#define NN 100000
#define NE 3200000
#define HD 64

// two-phase CSR build (packed 4-B pair entries: src | local_dst<<17)
#define NBUCK 256
#define BWID 392                                    // 256*392 = 100352 >= NN
#define SLACK 20480                                 // slots/bucket (8-granular runs, ~18.5K exp)
#define COLCAP 13568                                // real cols/bucket cap (12544 + ~9 sigma)
#define OVFCAP 512                                  // overflow pairs/bucket
#define CAP 24                                      // staged entries per bucket per block
#define P1_EPB 2048                                 // edges per partition block
#define P1_GRID ((NE + P1_EPB - 1) / P1_EPB)        // 1563
#define PSENT 0xFFFFFFFFu                           // sentinel pad entry

typedef int      v4i __attribute__((ext_vector_type(4)));
typedef int      v2i __attribute__((ext_vector_type(2)));
typedef _Float16 h4f __attribute__((ext_vector_type(4)));   // 4 halves = 8 B

__device__ __forceinline__ void fma4(float4& a, float s, const float4& b) {
    a.x = fmaf(s, b.x, a.x); a.y = fmaf(s, b.y, a.y);
    a.z = fmaf(s, b.z, a.z); a.w = fmaf(s, b.w, a.w);
}
__device__ __forceinline__ void addh4(float4& a, const h4f& b) {
    a.x += (float)b[0]; a.y += (float)b[1]; a.z += (float)b[2]; a.w += (float)b[3];
}

// ---------------- phase 1: bucket partition, LDS-staged, 1 drain/block ----------------
__global__ void __launch_bounds__(256) partition_kernel(
    const int* __restrict__ src, const int* __restrict__ dst,
    int* __restrict__ bctl, unsigned* __restrict__ pairs, v2i* __restrict__ povf) {
    __shared__ unsigned stage[NBUCK][CAP];
    __shared__ int cnt[NBUCK];
    int t = threadIdx.x;
    cnt[t] = 0;                         // NBUCK == blockDim == 256
    __syncthreads();
    const v4i* d4p = (const v4i*)dst;
    const v4i* s4p = (const v4i*)src;
    const int NE4 = NE / 4;
    int base4 = blockIdx.x * (P1_EPB / 4);
    #pragma unroll
    for (int it = 0; it < P1_EPB / 1024; it++) {
        int i = base4 + it * 256 + t;
        v4i d4 = (v4i){-1, -1, -1, -1};
        v4i s4 = (v4i){0, 0, 0, 0};
        if (i < NE4) {
            d4 = __builtin_nontemporal_load(d4p + i);
            s4 = __builtin_nontemporal_load(s4p + i);
        }
        #pragma unroll
        for (int k = 0; k < 4; k++) {
            int d = d4[k];
            if (d >= 0) {
                int b = (unsigned)d / BWID;
                int slot = atomicAdd(&cnt[b], 1);
                unsigned u = (unsigned)s4[k] | ((unsigned)(d - b * BWID) << 17);
                if (slot < CAP) {
                    stage[b][slot] = u;
                } else {                 // rare overflow -> separate region
                    int o = atomicAdd(&bctl[b * 16 + 2], 1);
                    v2i p; p[0] = s4[k]; p[1] = d;
                    if (o < OVFCAP) povf[(size_t)b * OVFCAP + o] = p;
                }
            }
        }
    }
    __syncthreads();
    // drain bucket t (single drain per block)
    int c_tot = cnt[t];
    int c = (c_tot > CAP) ? CAP : c_tot;
    int runs = (c + 7) >> 3;             // 0..3
    if (runs) {
        int slots = runs * 8;            // 8/16/24
        for (int m = c; m < slots; m++) stage[t][m] = PSENT;
        int gb = atomicAdd(&bctl[t * 16], slots);   // stays multiple of 8
        if (gb + slots <= SLACK) {
            v4i* gp = (v4i*)(pairs + (size_t)t * SLACK + gb);
            const v4i* sp = (const v4i*)&stage[t][0];
            #pragma unroll
            for (int m = 0; m < 6; m++) { if (m < runs * 2) gp[m] = sp[m]; }
        } else {
            for (int m = 0; m < slots && gb + m < SLACK; m++)
                pairs[(size_t)t * SLACK + gb + m] = stage[t][m];
        }
    }
    if (c_tot > 0) atomicAdd(&bctl[t * 16 + 1], c_tot);   // real contribution
}

// ---------------- phase 2: bucket scan + per-bucket hist + scan + LDS scatter ----------
__global__ void __launch_bounds__(256) csr_fill_kernel(
    const unsigned* __restrict__ pairs, const v2i* __restrict__ povf,
    const int* __restrict__ bctl, int* __restrict__ rowptr,
    float* __restrict__ dinv, int* __restrict__ col,
    _Float16* __restrict__ hA, _Float16* __restrict__ hB) {
    __shared__ int hist[BWID];
    __shared__ int rp[BWID];
    __shared__ int cur[BWID];
    __shared__ int sc[256];
    __shared__ int cols[COLCAP];
    int b = blockIdx.x, t = threadIdx.x;
    if (b == 0 && t < 64) {             // sentinel zero rows
        hA[(size_t)NN * 64 + t] = (_Float16)0.f;
        hB[(size_t)NN * 64 + t] = (_Float16)0.f;
    }
    int lo = b * BWID;
    int hi = min(lo + BWID, NN);
    int nw = hi - lo;
    // global bucket prefix scan (inclusive -> exclusive base for bucket b)
    int bcv = bctl[t * 16 + 1];
    sc[t] = bcv; __syncthreads();
    for (int off = 1; off < 256; off <<= 1) {
        int x = (t >= off) ? sc[t - off] : 0;
        __syncthreads();
        sc[t] += x;
        __syncthreads();
    }
    int base = (b > 0) ? sc[b - 1] : 0;
    if (b == 0 && t == 255) rowptr[NN] = sc[255];   // == NE
    __syncthreads();
    for (int i = t; i < BWID; i += 256) { hist[i] = 0; cur[i] = 0; }
    __syncthreads();
    int np = bctl[b * 16];     if (np > SLACK) np = SLACK;
    int nov = bctl[b * 16 + 2]; if (nov > OVFCAP) nov = OVFCAP;
    const unsigned* pb = pairs + (size_t)b * SLACK;
    const v2i* ob = povf + (size_t)b * OVFCAP;
    // pass 1: histogram (skip sentinels)
    for (int i = t; i < np; i += 256) {
        unsigned u = pb[i];
        if (u != PSENT) atomicAdd(&hist[(u >> 17) & 0x1FF], 1);
    }
    for (int i = t; i < nov; i += 256) {
        v2i p = ob[i];
        atomicAdd(&hist[p[1] - lo], 1);
    }
    __syncthreads();
    // exclusive scan of hist -> rp (2 elements per thread)
    int h0 = 0, s2 = 0;
    if (2 * t < BWID) {
        h0 = hist[2 * t];
        int h1 = (2 * t + 1 < BWID) ? hist[2 * t + 1] : 0;
        s2 = h0 + h1;
    }
    sc[t] = s2; __syncthreads();
    for (int off = 1; off < 256; off <<= 1) {
        int x = (t >= off) ? sc[t - off] : 0;
        __syncthreads();
        sc[t] += x;
        __syncthreads();
    }
    if (2 * t < BWID) {
        int ex = sc[t] - s2;
        rp[2 * t] = ex;
        if (2 * t + 1 < BWID) rp[2 * t + 1] = ex + h0;
    }
    __syncthreads();
    // rowptr + dinv slices (coalesced)
    for (int i = t; i < nw; i += 256) {
        rowptr[lo + i] = base + rp[i];
        dinv[lo + i] = 1.0f / sqrtf((float)(hist[i] + 1));  // +1 self-loop
    }
    // pass 2: scatter into LDS
    for (int i = t; i < np; i += 256) {
        unsigned u = pb[i];
        if (u != PSENT) {
            int li = (u >> 17) & 0x1FF;
            int slot = atomicAdd(&cur[li], 1);
            int o = rp[li] + slot;
            if (o < COLCAP) cols[o] = (int)(u & 0x1FFFF);
        }
    }
    for (int i = t; i < nov; i += 256) {
        v2i p = ob[i];
        int li = p[1] - lo;
        int slot = atomicAdd(&cur[li], 1);
        int o = rp[li] + slot;
        if (o < COLCAP) cols[o] = p[0];
    }
    __syncthreads();
    // contiguous col write (real count only)
    int nreal = bctl[b * 16 + 1]; if (nreal > COLCAP) nreal = COLCAP;
    for (int i = t; i < nreal; i += 256)
        col[base + i] = cols[i];
}

// ---------------- fused modality encoders + GCN layer-0 matmul ----------------
// Computes in fp32, stores hs = h*dinv as FP16.
__global__ void __launch_bounds__(256) encmm0_kernel(
    const float* __restrict__ xf, const float* __restrict__ xw, const float* __restrict__ xt,
    const float* __restrict__ Wf, const float* __restrict__ bf,
    const float* __restrict__ Ww, const float* __restrict__ bw,
    const float* __restrict__ Wt, const float* __restrict__ bt,
    const float* __restrict__ W0, const float* __restrict__ dinv,
    _Float16* __restrict__ h) {
    __shared__ float xin[64][32];    // fire[0..7], wea[8..19], ter[20..29]
    __shared__ float wenc[30][64];   // encoder weights (rows match xin cols)
    __shared__ float bs[192];        // encoder biases
    __shared__ float xs[64][36];     // encoder outputs for current 32-slice (+4 pad)
    __shared__ float ws[32][64];     // W0 rows for current slice
    int t = threadIdx.x;
    int n0 = blockIdx.x * 64;

    {   // stage raw inputs
        const float4* xf4 = (const float4*)xf;
        for (int i = t; i < 128; i += 256) {
            int n = i >> 1, q = i & 1;
            int gn = n0 + n;
            float4 v = make_float4(0, 0, 0, 0);
            if (gn < NN) v = xf4[(size_t)gn * 2 + q];
            *(float4*)&xin[n][q * 4] = v;
        }
        const float4* xw4 = (const float4*)xw;
        for (int i = t; i < 192; i += 256) {
            int n = i / 3, q = i - n * 3;
            int gn = n0 + n;
            float4 v = make_float4(0, 0, 0, 0);
            if (gn < NN) v = xw4[(size_t)gn * 3 + q];
            *(float4*)&xin[n][8 + q * 4] = v;
        }
        const float2* xt2 = (const float2*)xt;
        for (int i = t; i < 320; i += 256) {
            int n = i / 5, q = i - n * 5;
            int gn = n0 + n;
            float2 v = make_float2(0, 0);
            if (gn < NN) v = xt2[(size_t)gn * 5 + q];
            *(float2*)&xin[n][20 + q * 2] = v;
        }
        // stage encoder weights: rows 0-7 Wf, 8-19 Ww, 20-29 Wt
        for (int i = t; i < 480; i += 256) {
            int r = i >> 4, q = i & 15;
            float4 v;
            if (r < 8)       v = ((const float4*)Wf)[r * 16 + q];
            else if (r < 20) v = ((const float4*)Ww)[(r - 8) * 16 + q];
            else             v = ((const float4*)Wt)[(r - 20) * 16 + q];
            *(float4*)&wenc[r][q * 4] = v;
        }
        // stage encoder biases
        if (t < 192) bs[t] = (t < 64) ? bf[t] : (t < 128) ? bw[t - 64] : bt[t - 128];
    }

    int cg = t & 15, ng = t >> 4;
    int c0 = cg * 4;
    float4 acc[4];
    #pragma unroll
    for (int i = 0; i < 4; i++) acc[i] = make_float4(0, 0, 0, 0);

    for (int kq = 0; kq < 6; kq++) {
        __syncthreads();
        {   // stage W0 slice rows [kq*32, kq*32+32)
            const float4* W04 = (const float4*)W0;
            float4* ws4 = (float4*)&ws[0][0];
            for (int i = t; i < 512; i += 256)
                ws4[i] = W04[(size_t)kq * 512 + i];
        }
        // compute encoder outputs for this slice (uniform modality per kq)
        int coff = (kq < 2) ? kq * 32 : (kq < 4) ? (kq - 2) * 32 : (kq - 4) * 32;
        if (kq < 2) {
            for (int i = t; i < 2048; i += 256) {
                int n = i >> 5, kk = i & 31;
                float a = bs[kq * 32 + kk];
                #pragma unroll
                for (int k = 0; k < 8; k++) a = fmaf(xin[n][k], wenc[k][coff + kk], a);
                xs[n][kk] = fmaxf(a, 0.f);
            }
        } else if (kq < 4) {
            for (int i = t; i < 2048; i += 256) {
                int n = i >> 5, kk = i & 31;
                float a = bs[kq * 32 + kk];
                #pragma unroll
                for (int k = 0; k < 12; k++) a = fmaf(xin[n][8 + k], wenc[8 + k][coff + kk], a);
                xs[n][kk] = fmaxf(a, 0.f);
            }
        } else {
            for (int i = t; i < 2048; i += 256) {
                int n = i >> 5, kk = i & 31;
                float a = bs[kq * 32 + kk];
                #pragma unroll
                for (int k = 0; k < 10; k++) a = fmaf(xin[n][20 + k], wenc[20 + k][coff + kk], a);
                xs[n][kk] = fmaxf(a, 0.f);
            }
        }
        __syncthreads();
        // register-blocked fma over this 32-slice
        for (int k = 0; k < 32; k += 4) {
            float4 b0 = *(const float4*)&ws[k + 0][c0];
            float4 b1 = *(const float4*)&ws[k + 1][c0];
            float4 b2 = *(const float4*)&ws[k + 2][c0];
            float4 b3 = *(const float4*)&ws[k + 3][c0];
            #pragma unroll
            for (int i = 0; i < 4; i++) {
                float4 a = *(const float4*)&xs[ng * 4 + i][k];
                fma4(acc[i], a.x, b0); fma4(acc[i], a.y, b1);
                fma4(acc[i], a.z, b2); fma4(acc[i], a.w, b3);
            }
        }
    }
    h4f* h4 = (h4f*)h;
    #pragma unroll
    for (int i = 0; i < 4; i++) {
        int gn = n0 + ng * 4 + i;
        if (gn < NN) {
            float dn = dinv[gn];
            h4f v;
            v[0] = (_Float16)(acc[i].x * dn);
            v[1] = (_Float16)(acc[i].y * dn);
            v[2] = (_Float16)(acc[i].z * dn);
            v[3] = (_Float16)(acc[i].w * dn);
            h4[((unsigned)gn << 4) + cg] = v;
        }
    }
}

#define GATHER_BODY(E)                                              \
    {   int s_ = __shfl(pv, (E));                                   \
        h4f v_ = h4[((unsigned)s_ << 4) + q];                       \
        addh4(acc, v_); }

// ---------------- fused CSR gather + finalize + next-layer 64x64 matmul ----------------
// Round-14 layout (measured best): 8-B/lane fp16 loads, q=l&15, g=l>>4,
// 8-deep unroll, 32-bit addressing, hoisted self-row/bias/dinv.
__global__ void gather_mm_kernel(
    const int* __restrict__ col, const int* __restrict__ rowptr,
    const float* __restrict__ dinv, const _Float16* __restrict__ h,
    const float* __restrict__ bias, const float* __restrict__ W,
    _Float16* __restrict__ hout) {
    int t = threadIdx.x;
    int n = (blockIdx.x * 256 + t) >> 6;
    int l = t & 63;
    if (n >= NN) return;
    int g = l >> 4;      // edge sub-slot 0..3
    int q = l & 15;      // half4 slot 0..15
    const h4f* h4 = (const h4f*)h;
    // hoisted independent loads (in flight under the gather)
    float dn = dinv[n];
    h4f hnh = h4[((unsigned)n << 4) + q];
    float4 b4 = ((const float4*)bias)[q];
    float4 acc = make_float4(0, 0, 0, 0);
    int r0 = rowptr[n], r1 = rowptr[n + 1];
    for (int base = r0; base < r1; base += 64) {
        int cnt = min(64, r1 - base);
        int pv = NN;                          // sentinel: zero row
        if (l < cnt) pv = __builtin_nontemporal_load(col + base + l);
        int steps = (cnt + 3) >> 2;
        int j = 0;
        for (; j + 8 <= steps; j += 8) {      // 8 loads in flight (deg>=32 fast path)
            int s0 = __shfl(pv, (j + 0) * 4 + g);
            int s1 = __shfl(pv, (j + 1) * 4 + g);
            int s2 = __shfl(pv, (j + 2) * 4 + g);
            int s3 = __shfl(pv, (j + 3) * 4 + g);
            int s4 = __shfl(pv, (j + 4) * 4 + g);
            int s5 = __shfl(pv, (j + 5) * 4 + g);
            int s6 = __shfl(pv, (j + 6) * 4 + g);
            int s7 = __shfl(pv, (j + 7) * 4 + g);
            h4f v0 = h4[((unsigned)s0 << 4) + q];
            h4f v1 = h4[((unsigned)s1 << 4) + q];
            h4f v2 = h4[((unsigned)s2 << 4) + q];
            h4f v3 = h4[((unsigned)s3 << 4) + q];
            h4f v4 = h4[((unsigned)s4 << 4) + q];
            h4f v5 = h4[((unsigned)s5 << 4) + q];
            h4f v6 = h4[((unsigned)s6 << 4) + q];
            h4f v7 = h4[((unsigned)s7 << 4) + q];
            addh4(acc, v0); addh4(acc, v1); addh4(acc, v2); addh4(acc, v3);
            addh4(acc, v4); addh4(acc, v5); addh4(acc, v6); addh4(acc, v7);
        }
        for (; j + 4 <= steps; j += 4) {      // at most one
            int s0 = __shfl(pv, (j + 0) * 4 + g);
            int s1 = __shfl(pv, (j + 1) * 4 + g);
            int s2 = __shfl(pv, (j + 2) * 4 + g);
            int s3 = __shfl(pv, (j + 3) * 4 + g);
            h4f v0 = h4[((unsigned)s0 << 4) + q];
            h4f v1 = h4[((unsigned)s1 << 4) + q];
            h4f v2 = h4[((unsigned)s2 << 4) + q];
            h4f v3 = h4[((unsigned)s3 << 4) + q];
            addh4(acc, v0); addh4(acc, v1); addh4(acc, v2); addh4(acc, v3);
        }
        for (; j < steps; j++)                // at most 3
            GATHER_BODY(j * 4 + g)
    }
    acc.x += __shfl_xor(acc.x, 16); acc.y += __shfl_xor(acc.y, 16);
    acc.z += __shfl_xor(acc.z, 16); acc.w += __shfl_xor(acc.w, 16);
    acc.x += __shfl_xor(acc.x, 32); acc.y += __shfl_xor(acc.y, 32);
    acc.z += __shfl_xor(acc.z, 32); acc.w += __shfl_xor(acc.w, 32);
    // layer output r (all lanes; q-slot replicated)
    float4 r;
    r.x = fmaxf(fmaf(dn, acc.x + (float)hnh[0], b4.x), 0.f);
    r.y = fmaxf(fmaf(dn, acc.y + (float)hnh[1], b4.y), 0.f);
    r.z = fmaxf(fmaf(dn, acc.z + (float)hnh[2], b4.z), 0.f);
    r.w = fmaxf(fmaf(dn, acc.w + (float)hnh[3], b4.w), 0.f);
    // next-layer matmul: lane l computes output column l; W rows from L1
    float oc0 = 0.f, oc1 = 0.f, oc2 = 0.f, oc3 = 0.f;
    #pragma unroll
    for (int qq = 0; qq < 16; qq++) {
        float rx = __shfl(r.x, qq);
        float ry = __shfl(r.y, qq);
        float rz = __shfl(r.z, qq);
        float rw = __shfl(r.w, qq);
        oc0 = fmaf(rx, W[(qq * 4 + 0) * 64 + l], oc0);
        oc1 = fmaf(ry, W[(qq * 4 + 1) * 64 + l], oc1);
        oc2 = fmaf(rz, W[(qq * 4 + 2) * 64 + l], oc2);
        oc3 = fmaf(rw, W[(qq * 4 + 3) * 64 + l], oc3);
    }
    float oc = (oc0 + oc1) + (oc2 + oc3);
    __builtin_nontemporal_store((_Float16)(oc * dn), &hout[((unsigned)n << 6) + l]);
}

// ---------------- fused CSR gather + finalize + output MLP ----------------
__global__ void gather_mlp_kernel(
    const int* __restrict__ col, const int* __restrict__ rowptr,
    const float* __restrict__ dinv, const _Float16* __restrict__ h,
    const float* __restrict__ bias, const float* __restrict__ w1,
    const float* __restrict__ b1, const float* __restrict__ w2,
    const float* __restrict__ b2, float* __restrict__ out) {
    int t = threadIdx.x;
    int n = (blockIdx.x * 256 + t) >> 6;
    int l = t & 63;
    if (n >= NN) return;
    int g = l >> 4;
    int q = l & 15;
    const h4f* h4 = (const h4f*)h;
    float dn = dinv[n];
    h4f hnh = h4[((unsigned)n << 4) + q];
    float4 b4 = ((const float4*)bias)[q];
    float4 acc = make_float4(0, 0, 0, 0);
    int r0 = rowptr[n], r1 = rowptr[n + 1];
    for (int base = r0; base < r1; base += 64) {
        int cnt = min(64, r1 - base);
        int pv = NN;
        if (l < cnt) pv = __builtin_nontemporal_load(col + base + l);
        int steps = (cnt + 3) >> 2;
        int j = 0;
        for (; j + 8 <= steps; j += 8) {
            int s0 = __shfl(pv, (j + 0) * 4 + g);
            int s1 = __shfl(pv, (j + 1) * 4 + g);
            int s2 = __shfl(pv, (j + 2) * 4 + g);
            int s3 = __shfl(pv, (j + 3) * 4 + g);
            int s4 = __shfl(pv, (j + 4) * 4 + g);
            int s5 = __shfl(pv, (j + 5) * 4 + g);
            int s6 = __shfl(pv, (j + 6) * 4 + g);
            int s7 = __shfl(pv, (j + 7) * 4 + g);
            h4f v0 = h4[((unsigned)s0 << 4) + q];
            h4f v1 = h4[((unsigned)s1 << 4) + q];
            h4f v2 = h4[((unsigned)s2 << 4) + q];
            h4f v3 = h4[((unsigned)s3 << 4) + q];
            h4f v4 = h4[((unsigned)s4 << 4) + q];
            h4f v5 = h4[((unsigned)s5 << 4) + q];
            h4f v6 = h4[((unsigned)s6 << 4) + q];
            h4f v7 = h4[((unsigned)s7 << 4) + q];
            addh4(acc, v0); addh4(acc, v1); addh4(acc, v2); addh4(acc, v3);
            addh4(acc, v4); addh4(acc, v5); addh4(acc, v6); addh4(acc, v7);
        }
        for (; j + 4 <= steps; j += 4) {
            int s0 = __shfl(pv, (j + 0) * 4 + g);
            int s1 = __shfl(pv, (j + 1) * 4 + g);
            int s2 = __shfl(pv, (j + 2) * 4 + g);
            int s3 = __shfl(pv, (j + 3) * 4 + g);
            h4f v0 = h4[((unsigned)s0 << 4) + q];
            h4f v1 = h4[((unsigned)s1 << 4) + q];
            h4f v2 = h4[((unsigned)s2 << 4) + q];
            h4f v3 = h4[((unsigned)s3 << 4) + q];
            addh4(acc, v0); addh4(acc, v1); addh4(acc, v2); addh4(acc, v3);
        }
        for (; j < steps; j++)
            GATHER_BODY(j * 4 + g)
    }
    acc.x += __shfl_xor(acc.x, 16); acc.y += __shfl_xor(acc.y, 16);
    acc.z += __shfl_xor(acc.z, 16); acc.w += __shfl_xor(acc.w, 16);
    acc.x += __shfl_xor(acc.x, 32); acc.y += __shfl_xor(acc.y, 32);
    acc.z += __shfl_xor(acc.z, 32); acc.w += __shfl_xor(acc.w, 32);
    float4 r;
    r.x = fmaxf(fmaf(dn, acc.x + (float)hnh[0], b4.x), 0.f);
    r.y = fmaxf(fmaf(dn, acc.y + (float)hnh[1], b4.y), 0.f);
    r.z = fmaxf(fmaf(dn, acc.z + (float)hnh[2], b4.z), 0.f);
    r.w = fmaxf(fmaf(dn, acc.w + (float)hnh[3], b4.w), 0.f);
    // output MLP: hidden unit c = l&31 (w1 rows are L1-resident, coalesced)
    int c = l & 31;
    float a0 = b1[c], a1 = 0.f, a2p = 0.f, a3 = 0.f;
    #pragma unroll
    for (int qq = 0; qq < 16; qq++) {
        float rx = __shfl(r.x, qq);
        float ry = __shfl(r.y, qq);
        float rz = __shfl(r.z, qq);
        float rw = __shfl(r.w, qq);
        a0  = fmaf(rx, w1[(qq * 4 + 0) * 32 + c], a0);
        a1  = fmaf(ry, w1[(qq * 4 + 1) * 32 + c], a1);
        a2p = fmaf(rz, w1[(qq * 4 + 2) * 32 + c], a2p);
        a3  = fmaf(rw, w1[(qq * 4 + 3) * 32 + c], a3);
    }
    float a = (a0 + a1) + (a2p + a3);
    float v = fmaxf(a, 0.f) * w2[c];
    v += __shfl_xor(v, 1); v += __shfl_xor(v, 2);
    v += __shfl_xor(v, 4); v += __shfl_xor(v, 8);
    v += __shfl_xor(v, 16);
    if (l == 0) __builtin_nontemporal_store(v + b2[0], &out[n]);
}

extern "C" void kernel_launch(void* const* d_in, const int* in_sizes, int n_in,
                              void* d_out, int out_size, void* d_ws, size_t ws_size,
                              hipStream_t stream) {
    const float* xf = (const float*)d_in[0];
    const float* xw = (const float*)d_in[1];
    const float* xt = (const float*)d_in[2];
    const int*   ei = (const int*)d_in[3];
    const int*   src = ei;
    const int*   dst = ei + NE;
    const float* Wf = (const float*)d_in[4];
    const float* bf = (const float*)d_in[5];
    const float* Ww = (const float*)d_in[6];
    const float* bw = (const float*)d_in[7];
    const float* Wt = (const float*)d_in[8];
    const float* bt = (const float*)d_in[9];
    const float* W0 = (const float*)d_in[10];
    const float* b0 = (const float*)d_in[11];
    const float* W1 = (const float*)d_in[12];
    const float* b1 = (const float*)d_in[13];
    const float* W2 = (const float*)d_in[14];
    const float* b2 = (const float*)d_in[15];
    const float* ow1 = (const float*)d_in[16];
    const float* ob1 = (const float*)d_in[17];
    const float* ow2 = (const float*)d_in[18];
    const float* ob2 = (const float*)d_in[19];
    float* out = (float*)d_out;

    // workspace layout (~62 MB)
    char* w = (char*)d_ws;
    _Float16* hA  = (_Float16*)w;  w += (size_t)(NN + 1) * 64 * 2;   // 12.8 MB (+zero row)
    _Float16* hB  = (_Float16*)w;  w += (size_t)(NN + 1) * 64 * 2;   // 12.8 MB (+zero row)
    int*   col    = (int*)w;    w += (size_t)NE * 4;                 // 12.8 MB
    unsigned* pairs = (unsigned*)w; w += (size_t)NBUCK * SLACK * 4;  // 21 MB
    v2i*   povf   = (v2i*)w;    w += (size_t)NBUCK * OVFCAP * 8;     // 1 MB
    float* dinv   = (float*)w;  w += (size_t)NN * 4;
    int*   rowptr = (int*)w;    w += (size_t)(NN + 1) * 4;
    int*   bctl   = (int*)w;    w += (size_t)NBUCK * 16 * 4;         // 16 KB (padded lines)

    // ---- CSR build (two-phase, packed 4-B entries; reused by all 3 layers) ----
    hipMemsetAsync(bctl, 0, (size_t)NBUCK * 16 * 4, stream);
    partition_kernel<<<P1_GRID, 256, 0, stream>>>(src, dst, bctl, pairs, povf);
    csr_fill_kernel<<<NBUCK, 256, 0, stream>>>(pairs, povf, bctl, rowptr, dinv, col, hA, hB);

    // ---- layer 0: fused encoders + matmul (scaled) -> hA ----
    encmm0_kernel<<<(NN + 63) / 64, 256, 0, stream>>>(xf, xw, xt, Wf, bf, Ww, bw, Wt, bt, W0, dinv, hA);
    // ---- gather(b0) + mm(W1) : hA -> hB ----
    gather_mm_kernel<<<(NN * 64 + 255) / 256, 256, 0, stream>>>(col, rowptr, dinv, hA, b0, W1, hB);
    // ---- gather(b1) + mm(W2) : hB -> hA ----
    gather_mm_kernel<<<(NN * 64 + 255) / 256, 256, 0, stream>>>(col, rowptr, dinv, hB, b1, W2, hA);
    // ---- gather(b2) + output MLP : hA -> out ----
    gather_mlp_kernel<<<(NN * 64 + 255) / 256, 256, 0, stream>>>(col, rowptr, dinv, hA, b2, ow1, ob1, ow2, ob2, out);
}

// Round 17
// 520.294 us; speedup vs baseline: 1.1001x; 1.0569x over previous
//
#include <hip/hip_runtime.h>

#define NN 100000
#define NE 3200000
#define HD 64

// two-phase CSR build (packed 4-B pair entries: src | local_dst<<17)
#define NBUCK 256
#define BWID 392                                    // 256*392 = 100352 >= NN
#define SLACK 20480                                 // slots/bucket (8-granular runs)
#define COLCAP 13568                                // real cols/bucket cap (12544 + ~9 sigma)
#define OVFCAP 512                                  // overflow pairs/bucket
#define CAP 32                                      // staged entries per bucket per block
#define P1_EPB 4096                                 // edges per partition block
#define P1_GRID ((NE + P1_EPB - 1) / P1_EPB)        // 782
#define PSENT 0xFFFFFFFFu                           // sentinel pad entry

typedef int      v4i __attribute__((ext_vector_type(4)));
typedef int      v2i __attribute__((ext_vector_type(2)));
typedef _Float16 h4f __attribute__((ext_vector_type(4)));   // 4 halves = 8 B

__device__ __forceinline__ void fma4(float4& a, float s, const float4& b) {
    a.x = fmaf(s, b.x, a.x); a.y = fmaf(s, b.y, a.y);
    a.z = fmaf(s, b.z, a.z); a.w = fmaf(s, b.w, a.w);
}
// acc += (float)h  via v_fma_mix_f32 (fused f16 convert + f32 accumulate):
// one VALU op per element instead of cvt+add (the gather's dominant VALU cost).
__device__ __forceinline__ void addh4(float4& a, const h4f& b) {
    union { h4f h; unsigned u[2]; } cv; cv.h = b;
    float one = 1.0f;
    asm("v_fma_mix_f32 %0, %4, %6, %0 op_sel:[0,0,0] op_sel_hi:[1,0,0]\n\t"
        "v_fma_mix_f32 %1, %4, %6, %1 op_sel:[1,0,0] op_sel_hi:[1,0,0]\n\t"
        "v_fma_mix_f32 %2, %5, %6, %2 op_sel:[0,0,0] op_sel_hi:[1,0,0]\n\t"
        "v_fma_mix_f32 %3, %5, %6, %3 op_sel:[1,0,0] op_sel_hi:[1,0,0]"
        : "+v"(a.x), "+v"(a.y), "+v"(a.z), "+v"(a.w)
        : "v"(cv.u[0]), "v"(cv.u[1]), "v"(one));
}

// ---------------- phase 1: bucket partition, LDS-staged, 1 drain/block ----------------
__global__ void __launch_bounds__(256) partition_kernel(
    const int* __restrict__ src, const int* __restrict__ dst,
    int* __restrict__ bctl, unsigned* __restrict__ pairs, v2i* __restrict__ povf) {
    __shared__ unsigned stage[NBUCK][CAP];
    __shared__ int cnt[NBUCK];
    int t = threadIdx.x;
    cnt[t] = 0;                         // NBUCK == blockDim == 256
    __syncthreads();
    const v4i* d4p = (const v4i*)dst;
    const v4i* s4p = (const v4i*)src;
    const int NE4 = NE / 4;
    int base4 = blockIdx.x * (P1_EPB / 4);
    #pragma unroll
    for (int it = 0; it < P1_EPB / 1024; it++) {
        int i = base4 + it * 256 + t;
        v4i d4 = (v4i){-1, -1, -1, -1};
        v4i s4 = (v4i){0, 0, 0, 0};
        if (i < NE4) {
            d4 = __builtin_nontemporal_load(d4p + i);
            s4 = __builtin_nontemporal_load(s4p + i);
        }
        #pragma unroll
        for (int k = 0; k < 4; k++) {
            int d = d4[k];
            if (d >= 0) {
                int b = (unsigned)d / BWID;
                int slot = atomicAdd(&cnt[b], 1);
                unsigned u = (unsigned)s4[k] | ((unsigned)(d - b * BWID) << 17);
                if (slot < CAP) {
                    stage[b][slot] = u;
                } else {                 // rare overflow -> separate region
                    int o = atomicAdd(&bctl[b * 16 + 2], 1);
                    v2i p; p[0] = s4[k]; p[1] = d;
                    if (o < OVFCAP) povf[(size_t)b * OVFCAP + o] = p;
                }
            }
        }
    }
    __syncthreads();
    // drain bucket t (single drain per block)
    int c_tot = cnt[t];
    int c = (c_tot > CAP) ? CAP : c_tot;
    int runs = (c + 7) >> 3;             // 0..4
    if (runs) {
        int slots = runs * 8;            // 8..32
        for (int m = c; m < slots; m++) stage[t][m] = PSENT;
        int gb = atomicAdd(&bctl[t * 16], slots);   // stays multiple of 8
        if (gb + slots <= SLACK) {
            v4i* gp = (v4i*)(pairs + (size_t)t * SLACK + gb);
            const v4i* sp = (const v4i*)&stage[t][0];
            #pragma unroll
            for (int m = 0; m < 8; m++) { if (m < runs * 2) gp[m] = sp[m]; }
        } else {
            for (int m = 0; m < slots && gb + m < SLACK; m++)
                pairs[(size_t)t * SLACK + gb + m] = stage[t][m];
        }
    }
    if (c_tot > 0) atomicAdd(&bctl[t * 16 + 1], c_tot);   // real contribution
}

// ---------------- phase 2: bucket scan + per-bucket hist + scan + LDS scatter ----------
__global__ void __launch_bounds__(256) csr_fill_kernel(
    const unsigned* __restrict__ pairs, const v2i* __restrict__ povf,
    const int* __restrict__ bctl, int* __restrict__ rowptr,
    float* __restrict__ dinv, int* __restrict__ col,
    _Float16* __restrict__ hA, _Float16* __restrict__ hB) {
    __shared__ int hist[BWID];
    __shared__ int rp[BWID];
    __shared__ int cur[BWID];
    __shared__ int sc[256];
    __shared__ int cols[COLCAP];
    int b = blockIdx.x, t = threadIdx.x;
    if (b == 0 && t < 64) {             // sentinel zero rows
        hA[(size_t)NN * 64 + t] = (_Float16)0.f;
        hB[(size_t)NN * 64 + t] = (_Float16)0.f;
    }
    int lo = b * BWID;
    int hi = min(lo + BWID, NN);
    int nw = hi - lo;
    // global bucket prefix scan (inclusive -> exclusive base for bucket b)
    int bcv = bctl[t * 16 + 1];
    sc[t] = bcv; __syncthreads();
    for (int off = 1; off < 256; off <<= 1) {
        int x = (t >= off) ? sc[t - off] : 0;
        __syncthreads();
        sc[t] += x;
        __syncthreads();
    }
    int base = (b > 0) ? sc[b - 1] : 0;
    if (b == 0 && t == 255) rowptr[NN] = sc[255];   // == NE
    __syncthreads();
    for (int i = t; i < BWID; i += 256) { hist[i] = 0; cur[i] = 0; }
    __syncthreads();
    int np = bctl[b * 16];     if (np > SLACK) np = SLACK;
    int nov = bctl[b * 16 + 2]; if (nov > OVFCAP) nov = OVFCAP;
    const unsigned* pb = pairs + (size_t)b * SLACK;
    const v2i* ob = povf + (size_t)b * OVFCAP;
    // pass 1: histogram (skip sentinels)
    for (int i = t; i < np; i += 256) {
        unsigned u = pb[i];
        if (u != PSENT) atomicAdd(&hist[(u >> 17) & 0x1FF], 1);
    }
    for (int i = t; i < nov; i += 256) {
        v2i p = ob[i];
        atomicAdd(&hist[p[1] - lo], 1);
    }
    __syncthreads();
    // exclusive scan of hist -> rp (2 elements per thread)
    int h0 = 0, s2 = 0;
    if (2 * t < BWID) {
        h0 = hist[2 * t];
        int h1 = (2 * t + 1 < BWID) ? hist[2 * t + 1] : 0;
        s2 = h0 + h1;
    }
    sc[t] = s2; __syncthreads();
    for (int off = 1; off < 256; off <<= 1) {
        int x = (t >= off) ? sc[t - off] : 0;
        __syncthreads();
        sc[t] += x;
        __syncthreads();
    }
    if (2 * t < BWID) {
        int ex = sc[t] - s2;
        rp[2 * t] = ex;
        if (2 * t + 1 < BWID) rp[2 * t + 1] = ex + h0;
    }
    __syncthreads();
    // rowptr + dinv slices (coalesced)
    for (int i = t; i < nw; i += 256) {
        rowptr[lo + i] = base + rp[i];
        dinv[lo + i] = 1.0f / sqrtf((float)(hist[i] + 1));  // +1 self-loop
    }
    // pass 2: scatter into LDS
    for (int i = t; i < np; i += 256) {
        unsigned u = pb[i];
        if (u != PSENT) {
            int li = (u >> 17) & 0x1FF;
            int slot = atomicAdd(&cur[li], 1);
            int o = rp[li] + slot;
            if (o < COLCAP) cols[o] = (int)(u & 0x1FFFF);
        }
    }
    for (int i = t; i < nov; i += 256) {
        v2i p = ob[i];
        int li = p[1] - lo;
        int slot = atomicAdd(&cur[li], 1);
        int o = rp[li] + slot;
        if (o < COLCAP) cols[o] = p[0];
    }
    __syncthreads();
    // contiguous col write (real count only)
    int nreal = bctl[b * 16 + 1]; if (nreal > COLCAP) nreal = COLCAP;
    for (int i = t; i < nreal; i += 256)
        col[base + i] = cols[i];
}

// ---------------- fused modality encoders + GCN layer-0 matmul ----------------
// Computes in fp32, stores hs = h*dinv as FP16.
__global__ void __launch_bounds__(256) encmm0_kernel(
    const float* __restrict__ xf, const float* __restrict__ xw, const float* __restrict__ xt,
    const float* __restrict__ Wf, const float* __restrict__ bf,
    const float* __restrict__ Ww, const float* __restrict__ bw,
    const float* __restrict__ Wt, const float* __restrict__ bt,
    const float* __restrict__ W0, const float* __restrict__ dinv,
    _Float16* __restrict__ h) {
    __shared__ float xin[64][32];    // fire[0..7], wea[8..19], ter[20..29]
    __shared__ float wenc[30][64];   // encoder weights (rows match xin cols)
    __shared__ float bs[192];        // encoder biases
    __shared__ float xs[64][36];     // encoder outputs for current 32-slice (+4 pad)
    __shared__ float ws[32][64];     // W0 rows for current slice
    int t = threadIdx.x;
    int n0 = blockIdx.x * 64;

    {   // stage raw inputs
        const float4* xf4 = (const float4*)xf;
        for (int i = t; i < 128; i += 256) {
            int n = i >> 1, q = i & 1;
            int gn = n0 + n;
            float4 v = make_float4(0, 0, 0, 0);
            if (gn < NN) v = xf4[(size_t)gn * 2 + q];
            *(float4*)&xin[n][q * 4] = v;
        }
        const float4* xw4 = (const float4*)xw;
        for (int i = t; i < 192; i += 256) {
            int n = i / 3, q = i - n * 3;
            int gn = n0 + n;
            float4 v = make_float4(0, 0, 0, 0);
            if (gn < NN) v = xw4[(size_t)gn * 3 + q];
            *(float4*)&xin[n][8 + q * 4] = v;
        }
        const float2* xt2 = (const float2*)xt;
        for (int i = t; i < 320; i += 256) {
            int n = i / 5, q = i - n * 5;
            int gn = n0 + n;
            float2 v = make_float2(0, 0);
            if (gn < NN) v = xt2[(size_t)gn * 5 + q];
            *(float2*)&xin[n][20 + q * 2] = v;
        }
        // stage encoder weights: rows 0-7 Wf, 8-19 Ww, 20-29 Wt
        for (int i = t; i < 480; i += 256) {
            int r = i >> 4, q = i & 15;
            float4 v;
            if (r < 8)       v = ((const float4*)Wf)[r * 16 + q];
            else if (r < 20) v = ((const float4*)Ww)[(r - 8) * 16 + q];
            else             v = ((const float4*)Wt)[(r - 20) * 16 + q];
            *(float4*)&wenc[r][q * 4] = v;
        }
        // stage encoder biases
        if (t < 192) bs[t] = (t < 64) ? bf[t] : (t < 128) ? bw[t - 64] : bt[t - 128];
    }

    int cg = t & 15, ng = t >> 4;
    int c0 = cg * 4;
    float4 acc[4];
    #pragma unroll
    for (int i = 0; i < 4; i++) acc[i] = make_float4(0, 0, 0, 0);

    for (int kq = 0; kq < 6; kq++) {
        __syncthreads();
        {   // stage W0 slice rows [kq*32, kq*32+32)
            const float4* W04 = (const float4*)W0;
            float4* ws4 = (float4*)&ws[0][0];
            for (int i = t; i < 512; i += 256)
                ws4[i] = W04[(size_t)kq * 512 + i];
        }
        // compute encoder outputs for this slice (uniform modality per kq)
        int coff = (kq < 2) ? kq * 32 : (kq < 4) ? (kq - 2) * 32 : (kq - 4) * 32;
        if (kq < 2) {
            for (int i = t; i < 2048; i += 256) {
                int n = i >> 5, kk = i & 31;
                float a = bs[kq * 32 + kk];
                #pragma unroll
                for (int k = 0; k < 8; k++) a = fmaf(xin[n][k], wenc[k][coff + kk], a);
                xs[n][kk] = fmaxf(a, 0.f);
            }
        } else if (kq < 4) {
            for (int i = t; i < 2048; i += 256) {
                int n = i >> 5, kk = i & 31;
                float a = bs[kq * 32 + kk];
                #pragma unroll
                for (int k = 0; k < 12; k++) a = fmaf(xin[n][8 + k], wenc[8 + k][coff + kk], a);
                xs[n][kk] = fmaxf(a, 0.f);
            }
        } else {
            for (int i = t; i < 2048; i += 256) {
                int n = i >> 5, kk = i & 31;
                float a = bs[kq * 32 + kk];
                #pragma unroll
                for (int k = 0; k < 10; k++) a = fmaf(xin[n][20 + k], wenc[20 + k][coff + kk], a);
                xs[n][kk] = fmaxf(a, 0.f);
            }
        }
        __syncthreads();
        // register-blocked fma over this 32-slice
        for (int k = 0; k < 32; k += 4) {
            float4 b0 = *(const float4*)&ws[k + 0][c0];
            float4 b1 = *(const float4*)&ws[k + 1][c0];
            float4 b2 = *(const float4*)&ws[k + 2][c0];
            float4 b3 = *(const float4*)&ws[k + 3][c0];
            #pragma unroll
            for (int i = 0; i < 4; i++) {
                float4 a = *(const float4*)&xs[ng * 4 + i][k];
                fma4(acc[i], a.x, b0); fma4(acc[i], a.y, b1);
                fma4(acc[i], a.z, b2); fma4(acc[i], a.w, b3);
            }
        }
    }
    h4f* h4 = (h4f*)h;
    #pragma unroll
    for (int i = 0; i < 4; i++) {
        int gn = n0 + ng * 4 + i;
        if (gn < NN) {
            float dn = dinv[gn];
            h4f v;
            v[0] = (_Float16)(acc[i].x * dn);
            v[1] = (_Float16)(acc[i].y * dn);
            v[2] = (_Float16)(acc[i].z * dn);
            v[3] = (_Float16)(acc[i].w * dn);
            h4[((unsigned)gn << 4) + cg] = v;
        }
    }
}

#define GATHER_BODY(E)                                              \
    {   int s_ = __shfl(pv, (E));                                   \
        h4f v_ = h4[((unsigned)s_ << 4) + q];                       \
        addh4(acc, v_); }

// ---------------- fused CSR gather + finalize + next-layer 64x64 matmul ----------------
__global__ void gather_mm_kernel(
    const int* __restrict__ col, const int* __restrict__ rowptr,
    const float* __restrict__ dinv, const _Float16* __restrict__ h,
    const float* __restrict__ bias, const float* __restrict__ W,
    _Float16* __restrict__ hout) {
    int t = threadIdx.x;
    int n = (blockIdx.x * 256 + t) >> 6;
    int l = t & 63;
    if (n >= NN) return;
    int g = l >> 4;      // edge sub-slot 0..3
    int q = l & 15;      // half4 slot 0..15
    const h4f* h4 = (const h4f*)h;
    // hoisted independent loads (in flight under the gather)
    float dn = dinv[n];
    h4f hnh = h4[((unsigned)n << 4) + q];
    float4 b4 = ((const float4*)bias)[q];
    float4 acc = make_float4(0, 0, 0, 0);
    int r0 = rowptr[n], r1 = rowptr[n + 1];
    for (int base = r0; base < r1; base += 64) {
        int cnt = min(64, r1 - base);
        int pv = NN;                          // sentinel: zero row
        if (l < cnt) pv = __builtin_nontemporal_load(col + base + l);
        int steps = (cnt + 3) >> 2;
        int j = 0;
        for (; j + 8 <= steps; j += 8) {      // 8 loads in flight (deg>=32 fast path)
            int s0 = __shfl(pv, (j + 0) * 4 + g);
            int s1 = __shfl(pv, (j + 1) * 4 + g);
            int s2 = __shfl(pv, (j + 2) * 4 + g);
            int s3 = __shfl(pv, (j + 3) * 4 + g);
            int s4 = __shfl(pv, (j + 4) * 4 + g);
            int s5 = __shfl(pv, (j + 5) * 4 + g);
            int s6 = __shfl(pv, (j + 6) * 4 + g);
            int s7 = __shfl(pv, (j + 7) * 4 + g);
            h4f v0 = h4[((unsigned)s0 << 4) + q];
            h4f v1 = h4[((unsigned)s1 << 4) + q];
            h4f v2 = h4[((unsigned)s2 << 4) + q];
            h4f v3 = h4[((unsigned)s3 << 4) + q];
            h4f v4 = h4[((unsigned)s4 << 4) + q];
            h4f v5 = h4[((unsigned)s5 << 4) + q];
            h4f v6 = h4[((unsigned)s6 << 4) + q];
            h4f v7 = h4[((unsigned)s7 << 4) + q];
            addh4(acc, v0); addh4(acc, v1); addh4(acc, v2); addh4(acc, v3);
            addh4(acc, v4); addh4(acc, v5); addh4(acc, v6); addh4(acc, v7);
        }
        for (; j + 4 <= steps; j += 4) {      // at most one
            int s0 = __shfl(pv, (j + 0) * 4 + g);
            int s1 = __shfl(pv, (j + 1) * 4 + g);
            int s2 = __shfl(pv, (j + 2) * 4 + g);
            int s3 = __shfl(pv, (j + 3) * 4 + g);
            h4f v0 = h4[((unsigned)s0 << 4) + q];
            h4f v1 = h4[((unsigned)s1 << 4) + q];
            h4f v2 = h4[((unsigned)s2 << 4) + q];
            h4f v3 = h4[((unsigned)s3 << 4) + q];
            addh4(acc, v0); addh4(acc, v1); addh4(acc, v2); addh4(acc, v3);
        }
        for (; j < steps; j++)                // at most 3
            GATHER_BODY(j * 4 + g)
    }
    acc.x += __shfl_xor(acc.x, 16); acc.y += __shfl_xor(acc.y, 16);
    acc.z += __shfl_xor(acc.z, 16); acc.w += __shfl_xor(acc.w, 16);
    acc.x += __shfl_xor(acc.x, 32); acc.y += __shfl_xor(acc.y, 32);
    acc.z += __shfl_xor(acc.z, 32); acc.w += __shfl_xor(acc.w, 32);
    // layer output r (all lanes; q-slot replicated)
    float4 r;
    r.x = fmaxf(fmaf(dn, acc.x + (float)hnh[0], b4.x), 0.f);
    r.y = fmaxf(fmaf(dn, acc.y + (float)hnh[1], b4.y), 0.f);
    r.z = fmaxf(fmaf(dn, acc.z + (float)hnh[2], b4.z), 0.f);
    r.w = fmaxf(fmaf(dn, acc.w + (float)hnh[3], b4.w), 0.f);
    // next-layer matmul: lane l computes output column l; W rows from L1
    float oc0 = 0.f, oc1 = 0.f, oc2 = 0.f, oc3 = 0.f;
    #pragma unroll
    for (int qq = 0; qq < 16; qq++) {
        float rx = __shfl(r.x, qq);
        float ry = __shfl(r.y, qq);
        float rz = __shfl(r.z, qq);
        float rw = __shfl(r.w, qq);
        oc0 = fmaf(rx, W[(qq * 4 + 0) * 64 + l], oc0);
        oc1 = fmaf(ry, W[(qq * 4 + 1) * 64 + l], oc1);
        oc2 = fmaf(rz, W[(qq * 4 + 2) * 64 + l], oc2);
        oc3 = fmaf(rw, W[(qq * 4 + 3) * 64 + l], oc3);
    }
    float oc = (oc0 + oc1) + (oc2 + oc3);
    __builtin_nontemporal_store((_Float16)(oc * dn), &hout[((unsigned)n << 6) + l]);
}

// ---------------- fused CSR gather + finalize + output MLP ----------------
__global__ void gather_mlp_kernel(
    const int* __restrict__ col, const int* __restrict__ rowptr,
    const float* __restrict__ dinv, const _Float16* __restrict__ h,
    const float* __restrict__ bias, const float* __restrict__ w1,
    const float* __restrict__ b1, const float* __restrict__ w2,
    const float* __restrict__ b2, float* __restrict__ out) {
    int t = threadIdx.x;
    int n = (blockIdx.x * 256 + t) >> 6;
    int l = t & 63;
    if (n >= NN) return;
    int g = l >> 4;
    int q = l & 15;
    const h4f* h4 = (const h4f*)h;
    float dn = dinv[n];
    h4f hnh = h4[((unsigned)n << 4) + q];
    float4 b4 = ((const float4*)bias)[q];
    float4 acc = make_float4(0, 0, 0, 0);
    int r0 = rowptr[n], r1 = rowptr[n + 1];
    for (int base = r0; base < r1; base += 64) {
        int cnt = min(64, r1 - base);
        int pv = NN;
        if (l < cnt) pv = __builtin_nontemporal_load(col + base + l);
        int steps = (cnt + 3) >> 2;
        int j = 0;
        for (; j + 8 <= steps; j += 8) {
            int s0 = __shfl(pv, (j + 0) * 4 + g);
            int s1 = __shfl(pv, (j + 1) * 4 + g);
            int s2 = __shfl(pv, (j + 2) * 4 + g);
            int s3 = __shfl(pv, (j + 3) * 4 + g);
            int s4 = __shfl(pv, (j + 4) * 4 + g);
            int s5 = __shfl(pv, (j + 5) * 4 + g);
            int s6 = __shfl(pv, (j + 6) * 4 + g);
            int s7 = __shfl(pv, (j + 7) * 4 + g);
            h4f v0 = h4[((unsigned)s0 << 4) + q];
            h4f v1 = h4[((unsigned)s1 << 4) + q];
            h4f v2 = h4[((unsigned)s2 << 4) + q];
            h4f v3 = h4[((unsigned)s3 << 4) + q];
            h4f v4 = h4[((unsigned)s4 << 4) + q];
            h4f v5 = h4[((unsigned)s5 << 4) + q];
            h4f v6 = h4[((unsigned)s6 << 4) + q];
            h4f v7 = h4[((unsigned)s7 << 4) + q];
            addh4(acc, v0); addh4(acc, v1); addh4(acc, v2); addh4(acc, v3);
            addh4(acc, v4); addh4(acc, v5); addh4(acc, v6); addh4(acc, v7);
        }
        for (; j + 4 <= steps; j += 4) {
            int s0 = __shfl(pv, (j + 0) * 4 + g);
            int s1 = __shfl(pv, (j + 1) * 4 + g);
            int s2 = __shfl(pv, (j + 2) * 4 + g);
            int s3 = __shfl(pv, (j + 3) * 4 + g);
            h4f v0 = h4[((unsigned)s0 << 4) + q];
            h4f v1 = h4[((unsigned)s1 << 4) + q];
            h4f v2 = h4[((unsigned)s2 << 4) + q];
            h4f v3 = h4[((unsigned)s3 << 4) + q];
            addh4(acc, v0); addh4(acc, v1); addh4(acc, v2); addh4(acc, v3);
        }
        for (; j < steps; j++)
            GATHER_BODY(j * 4 + g)
    }
    acc.x += __shfl_xor(acc.x, 16); acc.y += __shfl_xor(acc.y, 16);
    acc.z += __shfl_xor(acc.z, 16); acc.w += __shfl_xor(acc.w, 16);
    acc.x += __shfl_xor(acc.x, 32); acc.y += __shfl_xor(acc.y, 32);
    acc.z += __shfl_xor(acc.z, 32); acc.w += __shfl_xor(acc.w, 32);
    float4 r;
    r.x = fmaxf(fmaf(dn, acc.x + (float)hnh[0], b4.x), 0.f);
    r.y = fmaxf(fmaf(dn, acc.y + (float)hnh[1], b4.y), 0.f);
    r.z = fmaxf(fmaf(dn, acc.z + (float)hnh[2], b4.z), 0.f);
    r.w = fmaxf(fmaf(dn, acc.w + (float)hnh[3], b4.w), 0.f);
    // output MLP: hidden unit c = l&31 (w1 rows are L1-resident, coalesced)
    int c = l & 31;
    float a0 = b1[c], a1 = 0.f, a2p = 0.f, a3 = 0.f;
    #pragma unroll
    for (int qq = 0; qq < 16; qq++) {
        float rx = __shfl(r.x, qq);
        float ry = __shfl(r.y, qq);
        float rz = __shfl(r.z, qq);
        float rw = __shfl(r.w, qq);
        a0  = fmaf(rx, w1[(qq * 4 + 0) * 32 + c], a0);
        a1  = fmaf(ry, w1[(qq * 4 + 1) * 32 + c], a1);
        a2p = fmaf(rz, w1[(qq * 4 + 2) * 32 + c], a2p);
        a3  = fmaf(rw, w1[(qq * 4 + 3) * 32 + c], a3);
    }
    float a = (a0 + a1) + (a2p + a3);
    float v = fmaxf(a, 0.f) * w2[c];
    v += __shfl_xor(v, 1); v += __shfl_xor(v, 2);
    v += __shfl_xor(v, 4); v += __shfl_xor(v, 8);
    v += __shfl_xor(v, 16);
    if (l == 0) __builtin_nontemporal_store(v + b2[0], &out[n]);
}

extern "C" void kernel_launch(void* const* d_in, const int* in_sizes, int n_in,
                              void* d_out, int out_size, void* d_ws, size_t ws_size,
                              hipStream_t stream) {
    const float* xf = (const float*)d_in[0];
    const float* xw = (const float*)d_in[1];
    const float* xt = (const float*)d_in[2];
    const int*   ei = (const int*)d_in[3];
    const int*   src = ei;
    const int*   dst = ei + NE;
    const float* Wf = (const float*)d_in[4];
    const float* bf = (const float*)d_in[5];
    const float* Ww = (const float*)d_in[6];
    const float* bw = (const float*)d_in[7];
    const float* Wt = (const float*)d_in[8];
    const float* bt = (const float*)d_in[9];
    const float* W0 = (const float*)d_in[10];
    const float* b0 = (const float*)d_in[11];
    const float* W1 = (const float*)d_in[12];
    const float* b1 = (const float*)d_in[13];
    const float* W2 = (const float*)d_in[14];
    const float* b2 = (const float*)d_in[15];
    const float* ow1 = (const float*)d_in[16];
    const float* ob1 = (const float*)d_in[17];
    const float* ow2 = (const float*)d_in[18];
    const float* ob2 = (const float*)d_in[19];
    float* out = (float*)d_out;

    // workspace layout (~62 MB)
    char* w = (char*)d_ws;
    _Float16* hA  = (_Float16*)w;  w += (size_t)(NN + 1) * 64 * 2;   // 12.8 MB (+zero row)
    _Float16* hB  = (_Float16*)w;  w += (size_t)(NN + 1) * 64 * 2;   // 12.8 MB (+zero row)
    int*   col    = (int*)w;    w += (size_t)NE * 4;                 // 12.8 MB
    unsigned* pairs = (unsigned*)w; w += (size_t)NBUCK * SLACK * 4;  // 21 MB
    v2i*   povf   = (v2i*)w;    w += (size_t)NBUCK * OVFCAP * 8;     // 1 MB
    float* dinv   = (float*)w;  w += (size_t)NN * 4;
    int*   rowptr = (int*)w;    w += (size_t)(NN + 1) * 4;
    int*   bctl   = (int*)w;    w += (size_t)NBUCK * 16 * 4;         // 16 KB (padded lines)

    // ---- CSR build (two-phase, packed 4-B entries; reused by all 3 layers) ----
    hipMemsetAsync(bctl, 0, (size_t)NBUCK * 16 * 4, stream);
    partition_kernel<<<P1_GRID, 256, 0, stream>>>(src, dst, bctl, pairs, povf);
    csr_fill_kernel<<<NBUCK, 256, 0, stream>>>(pairs, povf, bctl, rowptr, dinv, col, hA, hB);

    // ---- layer 0: fused encoders + matmul (scaled) -> hA ----
    encmm0_kernel<<<(NN + 63) / 64, 256, 0, stream>>>(xf, xw, xt, Wf, bf, Ww, bw, Wt, bt, W0, dinv, hA);
    // ---- gather(b0) + mm(W1) : hA -> hB ----
    gather_mm_kernel<<<(NN * 64 + 255) / 256, 256, 0, stream>>>(col, rowptr, dinv, hA, b0, W1, hB);
    // ---- gather(b1) + mm(W2) : hB -> hA ----
    gather_mm_kernel<<<(NN * 64 + 255) / 256, 256, 0, stream>>>(col, rowptr, dinv, hB, b1, W2, hA);
    // ---- gather(b2) + output MLP : hA -> out ----
    gather_mlp_kernel<<<(NN * 64 + 255) / 256, 256, 0, stream>>>(col, rowptr, dinv, hA, b2, ow1, ob1, ow2, ob2, out);
}